// Round 5
// baseline (1546.695 us; speedup 1.0000x reference)
//
#include <hip/hip_runtime.h>
#include <hip/hip_bf16.h>

constexpr int N = 16384;   // points
constexpr int KNN = 10;
constexpr int CF = 64;     // feature channels per edgeconv

#define FBIG 1e30f

typedef __attribute__((ext_vector_type(8))) __bf16 bfv8;
typedef __attribute__((ext_vector_type(4))) float f32x4;

// ---------- top-k insert (replace-max) ----------
#define TOPK_INSERT(dval, jval)                                            \
  if ((dval) < bmax) {                                                     \
    float mv = bd[0]; int slot = 0;                                        \
    _Pragma("unroll") for (int s_ = 1; s_ < 10; ++s_)                      \
      if (bd[s_] > mv) { mv = bd[s_]; slot = s_; }                         \
    _Pragma("unroll") for (int s_ = 0; s_ < 10; ++s_)                      \
      if (slot == s_) { bd[s_] = (dval); bi[s_] = (jval); }                \
    bmax = bd[0];                                                          \
    _Pragma("unroll") for (int s_ = 1; s_ < 10; ++s_)                      \
      bmax = fmaxf(bmax, bd[s_]);                                          \
  }

__device__ inline ushort bf16_rne(float x) {
  unsigned u = __float_as_uint(x);
  return (ushort)((u + 0x7FFFu + ((u >> 16) & 1u)) >> 16);
}
__device__ inline float bf16_to_f(ushort h) { return __uint_as_float(((unsigned)h) << 16); }

// ---------- pack x (3ch) into float4 with sq norm ----------
__global__ __launch_bounds__(256) void pack3_kernel(const float* __restrict__ X,
                                                    float4* __restrict__ xp) {
  int i = blockIdx.x * 256 + threadIdx.x;
  float x0 = X[3 * i], x1 = X[3 * i + 1], x2 = X[3 * i + 2];
  float s = fmaf(x0, x0, fmaf(x1, x1, x2 * x2));
  xp[i] = make_float4(x0, x1, x2, s);
}

// ---------- fused 64-ch prep: bf16 hi/lo split + sq norm (one pass over X) ----------
__global__ __launch_bounds__(256) void prep128s_kernel(const float* __restrict__ X,
                                                       ushort* __restrict__ Xp,
                                                       float* __restrict__ sq) {
  int i = blockIdx.x * 256 + threadIdx.x;  // one float4 per thread; 16 threads per row
  int n = i >> 4, k4 = (i & 15) << 2;
  float4 v = ((const float4*)X)[i];
  float vv[4] = {v.x, v.y, v.z, v.w};
  ushort h[4], lo[4];
#pragma unroll
  for (int k = 0; k < 4; ++k) {
    h[k] = bf16_rne(vv[k]);
    lo[k] = bf16_rne(vv[k] - bf16_to_f(h[k]));
  }
  ushort* row = Xp + (size_t)n * 128;
  *(ushort4*)(row + k4) = make_ushort4(h[0], h[1], h[2], h[3]);
  *(ushort4*)(row + 64 + k4) = make_ushort4(lo[0], lo[1], lo[2], lo[3]);
  float ps = fmaf(vv[0], vv[0], fmaf(vv[1], vv[1], fmaf(vv[2], vv[2], vv[3] * vv[3])));
#pragma unroll
  for (int m = 1; m < 16; m <<= 1) ps += __shfl_xor(ps, m, 16);
  if ((threadIdx.x & 15) == 0) sq[n] = ps;
}

// ================= kNN kernels: single-barrier pipelined compaction =================
// Block: 64 rows x col-range (3-way split of 256 64-col tiles -> 85/85/86 tiles).
// grid = 256 rowgroups x 3 = 768 = exactly 3 blocks/CU (LDS 49.8KB*3=149KB, VGPR<=170).
// Per tile (ONE barrier): prefetch B(t+1) -> barrier -> owner lanes drain tile t-1's
// append buffer (other buffer) + refresh tau -> all lanes MFMA/dist + append-if(d<tau).
// tau staleness only admits extra candidates, never drops a true top-10 entry.
// Appends per row per tile <= 64 cols = CAP exactly -> no overflow check needed.
constexpr int CAP = 64;

#define KNN_SHARED                                                         \
  __shared__ float bufD[2][64 * 65];                                       \
  __shared__ ushort bufI[2][64 * 66];                                      \
  __shared__ float tau[64];                                                \
  __shared__ int cnt[2][64];

#define KNN_DRAIN(pp)                                                      \
  if (l < 16) {                                                            \
    const int rloc = w * 16 + l;                                           \
    const int c = cnt[pp][rloc];                                           \
    const float* bD = &bufD[pp][rloc * 65];                                \
    const ushort* bI = &bufI[pp][rloc * 66];                               \
    _Pragma("unroll 1") for (int j = 0; j < c; ++j) {                      \
      float d = bD[j];                                                     \
      int ii = (int)bI[j];                                                 \
      TOPK_INSERT(d, ii);                                                  \
    }                                                                      \
    cnt[pp][rloc] = 0;                                                     \
    tau[rloc] = bmax;                                                      \
  }

// ---------- kNN for C=3, exact fp32 distances (cancellation-sensitive: keep fp32!) ----------
__global__ __launch_bounds__(256, 3) void knn3c_kernel(const float4* __restrict__ xp,
                                                       float* __restrict__ dpart,
                                                       int* __restrict__ ipart) {
  KNN_SHARED
  __shared__ float4 rowsS[64];

  const int tid = threadIdx.x;
  const int w = tid >> 6;
  const int l = tid & 63;
  const int lp = l & 15;
  const int g = l >> 4;
  const int bid = blockIdx.x;
  const int rg = bid / 3;
  const int cs = bid % 3;
  const int row_base = rg * 64;
  const int t0 = (256 * cs) / 3, t1 = (256 * (cs + 1)) / 3;

  if (tid < 64) {
    rowsS[tid] = xp[row_base + tid];
    tau[tid] = FBIG;
    cnt[0][tid] = 0;
    cnt[1][tid] = 0;
  }
  __syncthreads();

  float4 rw[16];
#pragma unroll
  for (int rt = 0; rt < 4; ++rt)
#pragma unroll
    for (int r = 0; r < 4; ++r) rw[rt * 4 + r] = rowsS[rt * 16 + g * 4 + r];

  float bd[10]; int bi[10]; float bmax = FBIG;
#pragma unroll
  for (int s = 0; s < 10; ++s) { bd[s] = FBIG; bi[s] = 0x7ffffff; }

  float4 ocur = xp[t0 * 64 + w * 16 + lp];
  for (int t = t0; t < t1; ++t) {
    const int p = (t - t0) & 1, pp = p ^ 1;
    float4 onx;
    if (t + 1 < t1) onx = xp[(t + 1) * 64 + w * 16 + lp];  // prefetch: hides latency
    __syncthreads();  // appends(t-1) visible; drain(t-2) done
    KNN_DRAIN(pp)     // overlaps with other waves' dist/epilogue
    const int lcol = t * 64 + w * 16 + lp;
#pragma unroll
    for (int rt = 0; rt < 4; ++rt) {
      f32x4 taur = *(const f32x4*)&tau[rt * 16 + g * 4];
#pragma unroll
      for (int r = 0; r < 4; ++r) {
        const float4 m = rw[rt * 4 + r];
        float dot = fmaf(m.x, ocur.x, fmaf(m.y, ocur.y, m.z * ocur.z));
        float d = fmaf(-2.f, dot, m.w + ocur.w);  // same chain as validated knn3
        if (d < taur[r]) {
          int rloc = rt * 16 + g * 4 + r;
          int pos = atomicAdd(&cnt[p][rloc], 1);
          bufD[p][rloc * 65 + pos] = d;
          bufI[p][rloc * 66 + pos] = (ushort)lcol;
        }
      }
    }
    ocur = onx;
  }
  __syncthreads();
  { const int pf = (t1 - 1 - t0) & 1; KNN_DRAIN(pf) }

  if (l < 16) {
    const int row = row_base + w * 16 + l;
    float* dp = dpart + ((size_t)cs * N + row) * 10;
    int* ip = ipart + ((size_t)cs * N + row) * 10;
#pragma unroll
    for (int s = 0; s < 10; ++s) { dp[s] = bd[s]; ip[s] = bi[s]; }
  }
}

// ---------- kNN for C=64 via bf16-split MFMA ----------
__global__ __launch_bounds__(256, 3) void knn64c_kernel(const ushort* __restrict__ Xp,
                                                        const float* __restrict__ sq,
                                                        float* __restrict__ dpart,
                                                        int* __restrict__ ipart) {
  KNN_SHARED

  const int tid = threadIdx.x;
  const int w = tid >> 6;
  const int l = tid & 63;
  const int lp = l & 15;
  const int g = l >> 4;
  const int lk = g * 8;
  const int bid = blockIdx.x;
  const int rg = bid / 3;
  const int cs = bid % 3;
  const int row_base = rg * 64;
  const int t0 = (256 * cs) / 3, t1 = (256 * (cs + 1)) / 3;

  if (tid < 64) { tau[tid] = FBIG; cnt[0][tid] = 0; cnt[1][tid] = 0; }

  // A fragments for all 4 row-tiles, pinned in registers (64 VGPRs)
  bfv8 aH1[4], aH2[4], aL1[4], aL2[4];
#pragma unroll
  for (int rt = 0; rt < 4; ++rt) {
    const size_t ao = (size_t)(row_base + rt * 16 + lp) * 128 + lk;
    aH1[rt] = *(const bfv8*)&Xp[ao];
    aH2[rt] = *(const bfv8*)&Xp[ao + 32];
    aL1[rt] = *(const bfv8*)&Xp[ao + 64];
    aL2[rt] = *(const bfv8*)&Xp[ao + 96];
  }
  float sqi_r[16];
#pragma unroll
  for (int rt = 0; rt < 4; ++rt)
#pragma unroll
    for (int r = 0; r < 4; ++r) sqi_r[rt * 4 + r] = sq[row_base + rt * 16 + g * 4 + r];

  float bd[10]; int bi[10]; float bmax = FBIG;
#pragma unroll
  for (int s = 0; s < 10; ++s) { bd[s] = FBIG; bi[s] = 0x7ffffff; }

  __syncthreads();

  bfv8 bc[4];
  float sjc;
  {
    const int bcol = t0 * 64 + w * 16 + lp;
    const size_t bo = (size_t)bcol * 128 + lk;
    bc[0] = *(const bfv8*)&Xp[bo];
    bc[1] = *(const bfv8*)&Xp[bo + 32];
    bc[2] = *(const bfv8*)&Xp[bo + 64];
    bc[3] = *(const bfv8*)&Xp[bo + 96];
    sjc = sq[bcol];
  }

  for (int t = t0; t < t1; ++t) {
    const int p = (t - t0) & 1, pp = p ^ 1;
    bfv8 bn[4]; float sjn;
    if (t + 1 < t1) {  // prefetch next tile's B frags: load latency hidden behind this tile
      const int bcol = (t + 1) * 64 + w * 16 + lp;
      const size_t bo = (size_t)bcol * 128 + lk;
      bn[0] = *(const bfv8*)&Xp[bo];
      bn[1] = *(const bfv8*)&Xp[bo + 32];
      bn[2] = *(const bfv8*)&Xp[bo + 64];
      bn[3] = *(const bfv8*)&Xp[bo + 96];
      sjn = sq[bcol];
    }
    __syncthreads();  // appends(t-1) visible; drain(t-2) done
    KNN_DRAIN(pp)     // owner lanes; overlaps other waves' MFMA phase
    const int lcol = t * 64 + w * 16 + lp;
#pragma unroll
    for (int rt = 0; rt < 4; ++rt) {
      f32x4 acc = {0.f, 0.f, 0.f, 0.f};
      acc = __builtin_amdgcn_mfma_f32_16x16x32_bf16(aH1[rt], bc[0], acc, 0, 0, 0);
      acc = __builtin_amdgcn_mfma_f32_16x16x32_bf16(aH2[rt], bc[1], acc, 0, 0, 0);
      acc = __builtin_amdgcn_mfma_f32_16x16x32_bf16(aH1[rt], bc[2], acc, 0, 0, 0);
      acc = __builtin_amdgcn_mfma_f32_16x16x32_bf16(aH2[rt], bc[3], acc, 0, 0, 0);
      acc = __builtin_amdgcn_mfma_f32_16x16x32_bf16(aL1[rt], bc[0], acc, 0, 0, 0);
      acc = __builtin_amdgcn_mfma_f32_16x16x32_bf16(aL2[rt], bc[1], acc, 0, 0, 0);
      f32x4 taur = *(const f32x4*)&tau[rt * 16 + g * 4];
#pragma unroll
      for (int r = 0; r < 4; ++r) {
        float d = fmaf(-2.f, acc[r], sqi_r[rt * 4 + r] + sjc);
        if (d < taur[r]) {
          int rloc = rt * 16 + g * 4 + r;
          int pos = atomicAdd(&cnt[p][rloc], 1);
          bufD[p][rloc * 65 + pos] = d;
          bufI[p][rloc * 66 + pos] = (ushort)lcol;
        }
      }
    }
    bc[0] = bn[0]; bc[1] = bn[1]; bc[2] = bn[2]; bc[3] = bn[3]; sjc = sjn;
  }
  __syncthreads();
  { const int pf = (t1 - 1 - t0) & 1; KNN_DRAIN(pf) }

  if (l < 16) {
    const int row = row_base + w * 16 + l;
    float* dp = dpart + ((size_t)cs * N + row) * 10;
    int* ip = ipart + ((size_t)cs * N + row) * 10;
#pragma unroll
    for (int s = 0; s < 10; ++s) { dp[s] = bd[s]; ip[s] = bi[s]; }
  }
}

// ---------- merge S partial top-10 lists per row ----------
template <int S>
__global__ __launch_bounds__(256) void merge_kernel(const float* __restrict__ dpart,
                                                    const int* __restrict__ ipart,
                                                    int* __restrict__ idx_out) {
  const int row = blockIdx.x * 256 + threadIdx.x;
  float d[S * 10]; int id_[S * 10];
#pragma unroll
  for (int p = 0; p < S; ++p)
#pragma unroll
    for (int s = 0; s < 10; ++s) {
      d[p * 10 + s] = dpart[((size_t)p * N + row) * 10 + s];
      id_[p * 10 + s] = ipart[((size_t)p * N + row) * 10 + s];
    }
#pragma unroll
  for (int t = 0; t < 10; ++t) {
    float dm = d[0]; int im = id_[0]; int slot = 0;
#pragma unroll
    for (int e = 1; e < S * 10; ++e) {
      bool better = (d[e] < dm) || (d[e] == dm && id_[e] < im);
      if (better) { dm = d[e]; im = id_[e]; slot = e; }
    }
    idx_out[(size_t)row * 10 + t] = im;
#pragma unroll
    for (int e = 0; e < S * 10; ++e)
      if (e == slot) d[e] = FBIG;
  }
}

// ---------- u = x*W_bot ; v = x*(W_top - W_bot) + b ----------
__global__ __launch_bounds__(256) void uv_kernel(const float* __restrict__ Xf, int CIN,
                                                 const float* __restrict__ W,
                                                 const float* __restrict__ bias,
                                                 float* __restrict__ U, float* __restrict__ V) {
  int tid = threadIdx.x;
  int c = tid & 63, p = tid >> 6;
  int n = blockIdx.x * 4 + p;
  const float* xr = Xf + (size_t)n * CIN;
  float vt = 0.f, vb = 0.f;
  for (int m = 0; m < CIN; ++m) {
    float xm = xr[m];
    vt = fmaf(xm, W[m * 64 + c], vt);
    vb = fmaf(xm, W[(CIN + m) * 64 + c], vb);
  }
  U[(size_t)n * 64 + c] = vb;
  V[(size_t)n * 64 + c] = vt - vb + bias[c];
}

// ---------- BN batch stats ----------
__global__ __launch_bounds__(256) void stats_kernel(const float* __restrict__ U,
                                                    const float* __restrict__ V,
                                                    const int* __restrict__ idx,
                                                    float* __restrict__ accum) {
  int tid = threadIdx.x;
  int c = tid & 63, p = tid >> 6;
  int base = blockIdx.x * 64;  // 256 blocks x 64 points
  float s = 0.f, s2 = 0.f;
  for (int ch = 0; ch < 16; ++ch) {
    int n = base + ch * 4 + p;
    float vn = V[(size_t)n * 64 + c];
    const int* in_ = idx + (size_t)n * 10;
#pragma unroll
    for (int k = 0; k < 10; ++k) {
      float h = vn + U[(size_t)in_[k] * 64 + c];
      s += h;
      s2 = fmaf(h, h, s2);
    }
  }
  __shared__ float red[256], red2[256];
  red[tid] = s; red2[tid] = s2;
  __syncthreads();
  if (tid < 64) {
    float ts = red[tid] + red[64 + tid] + red[128 + tid] + red[192 + tid];
    float t2 = red2[tid] + red2[64 + tid] + red2[128 + tid] + red2[192 + tid];
    atomicAdd(&accum[tid], ts);
    atomicAdd(&accum[64 + tid], t2);
  }
}

__global__ void bnfin_kernel(const float* __restrict__ accum,
                             const float* __restrict__ gamma,
                             const float* __restrict__ beta,
                             float* __restrict__ scale, float* __restrict__ shift) {
  int c = threadIdx.x;  // 64
  float inv = 1.f / (float)(N * KNN);
  float mu = accum[c] * inv;
  float var = accum[64 + c] * inv - mu * mu;
  float sc = gamma[c] * rsqrtf(var + 1e-5f);
  scale[c] = sc;
  shift[c] = fmaf(-mu, sc, beta[c]);
}

// ---------- apply (BN) + ReLU + max over k ----------
__global__ __launch_bounds__(256) void apply_kernel(const float* __restrict__ U,
                                                    const float* __restrict__ V,
                                                    const int* __restrict__ idx,
                                                    const float* __restrict__ scale,
                                                    const float* __restrict__ shift,
                                                    int use_bn, float* __restrict__ Fout) {
  int tid = threadIdx.x;
  int c = tid & 63, p = tid >> 6;
  int n = blockIdx.x * 4 + p;
  float sc = use_bn ? scale[c] : 1.f;
  float sh = use_bn ? shift[c] : 0.f;
  float vn = V[(size_t)n * 64 + c];
  const int* in_ = idx + (size_t)n * 10;
  float m = 0.f;
#pragma unroll
  for (int k = 0; k < 10; ++k) {
    float h = vn + U[(size_t)in_[k] * 64 + c];
    m = fmaxf(m, fmaf(h, sc, sh));
  }
  Fout[(size_t)n * 64 + c] = m;
}

// ---------- segment max pooling, 2-stage ----------
__global__ __launch_bounds__(256) void pool1_kernel(const float* __restrict__ f1,
                                                    const float* __restrict__ f2,
                                                    const float* __restrict__ f3,
                                                    const float* __restrict__ f4,
                                                    const int* __restrict__ n_pts,
                                                    float* __restrict__ Pp) {
  int b = blockIdx.x >> 2;
  int q = blockIdx.x & 3;
  int c = threadIdx.x;
  int off = 0;
  for (int i = 0; i < b; ++i) off += n_pts[i];
  int cnt_ = n_pts[b];
  int s0 = off + (cnt_ * q) / 4;
  int s1 = off + (cnt_ * (q + 1)) / 4;
  const float* f = (c < 64) ? f1 : (c < 128) ? f2 : (c < 192) ? f3 : f4;
  int ch = c & 63;
  float m = -3.4e38f;
  for (int t = s0; t < s1; ++t) m = fmaxf(m, f[(size_t)t * 64 + ch]);
  Pp[((size_t)q * 64 + b) * 256 + c] = m;
}

__global__ __launch_bounds__(256) void pool2_kernel(const float* __restrict__ Pp,
                                                    float* __restrict__ P) {
  int b = blockIdx.x;
  int c = threadIdx.x;
  float m = Pp[(size_t)b * 256 + c];
#pragma unroll
  for (int q = 1; q < 4; ++q) m = fmaxf(m, Pp[((size_t)q * 64 + b) * 256 + c]);
  P[b * 256 + c] = m;
}

// ---------- head: tanh(P@Wp + bp), L2 normalize rows ----------
__global__ __launch_bounds__(128) void head_kernel(const float* __restrict__ P,
                                                   const float* __restrict__ Wp,
                                                   const float* __restrict__ bp,
                                                   float* __restrict__ out) {
  int b = blockIdx.x;
  int c = threadIdx.x;
  __shared__ float ps[256];
  ps[c] = P[b * 256 + c];
  ps[128 + c] = P[b * 256 + 128 + c];
  __syncthreads();
  float acc = bp[c];
  for (int m = 0; m < 256; ++m) acc = fmaf(ps[m], Wp[m * 128 + c], acc);
  float t = tanhf(acc);
  __shared__ float red[128];
  red[c] = t * t;
  __syncthreads();
  for (int s = 64; s > 0; s >>= 1) {
    if (c < s) red[c] += red[c + s];
    __syncthreads();
  }
  float nrm = sqrtf(red[0]);
  out[b * 128 + c] = t / (nrm + 1e-9f);
}

extern "C" void kernel_launch(void* const* d_in, const int* in_sizes, int n_in,
                              void* d_out, int out_size, void* d_ws, size_t ws_size,
                              hipStream_t stream) {
  const float* x = (const float*)d_in[0];
  const int* n_pts = (const int*)d_in[1];
  const float* W1 = (const float*)d_in[2];
  const float* b1 = (const float*)d_in[3];
  const float* g1 = (const float*)d_in[4];
  const float* be1 = (const float*)d_in[5];
  const float* W2 = (const float*)d_in[6];
  const float* b2 = (const float*)d_in[7];
  const float* W3 = (const float*)d_in[8];
  const float* b3 = (const float*)d_in[9];
  const float* g3 = (const float*)d_in[10];
  const float* be3 = (const float*)d_in[11];
  const float* W4 = (const float*)d_in[12];
  const float* b4 = (const float*)d_in[13];
  const float* Wp = (const float*)d_in[14];
  const float* bp = (const float*)d_in[15];
  float* out = (float*)d_out;

  char* w = (char*)d_ws;
  auto alloc = [&](size_t bytes) {
    char* p = w;
    w += (bytes + 255) & ~(size_t)255;
    return p;
  };
  const size_t FS = (size_t)N * 64 * 4;
  float* f1 = (float*)alloc(FS);
  float* f2 = (float*)alloc(FS);
  float* f3 = (float*)alloc(FS);
  float* f4 = (float*)alloc(FS);
  float* Ub = (float*)alloc(FS);   // overlaid: Xp128 (N*128 ushorts = FS bytes)
  float* Vb = (float*)alloc(FS);   // overlaid: xp (N float4 = FS/4)
  float* sqb = (float*)alloc((size_t)N * 4);
  float* dpartf = (float*)alloc((size_t)4 * N * 10 * 4);
  int* iparti = (int*)alloc((size_t)4 * N * 10 * 4);
  int* idxb = (int*)alloc((size_t)N * 10 * 4);
  float* accum = (float*)alloc(512);
  float* scaleb = (float*)alloc(256);
  float* shiftb = (float*)alloc(256);
  float* Pb = (float*)alloc((size_t)64 * 256 * 4);
  float* Ppart = (float*)alloc((size_t)4 * 64 * 256 * 4);
  ushort* Xp128 = (ushort*)Ub;
  float4* xp = (float4*)Vb;
  (void)ws_size; (void)n_in; (void)in_sizes; (void)out_size;

  auto run_layer = [&](const float* fin, int cin, const float* W, const float* b,
                       const float* g, const float* be, int use_bn, float* fout) {
    if (cin == 3) {
      pack3_kernel<<<N / 256, 256, 0, stream>>>(fin, xp);
      knn3c_kernel<<<768, 256, 0, stream>>>(xp, dpartf, iparti);
    } else {
      prep128s_kernel<<<N * 64 / 4 / 256, 256, 0, stream>>>(fin, Xp128, sqb);
      knn64c_kernel<<<768, 256, 0, stream>>>(Xp128, sqb, dpartf, iparti);
    }
    merge_kernel<3><<<N / 256, 256, 0, stream>>>(dpartf, iparti, idxb);
    uv_kernel<<<N / 4, 256, 0, stream>>>(fin, cin, W, b, Ub, Vb);
    if (use_bn) {
      hipMemsetAsync(accum, 0, 512, stream);
      stats_kernel<<<256, 256, 0, stream>>>(Ub, Vb, idxb, accum);
      bnfin_kernel<<<1, 64, 0, stream>>>(accum, g, be, scaleb, shiftb);
    }
    apply_kernel<<<N / 4, 256, 0, stream>>>(Ub, Vb, idxb, scaleb, shiftb, use_bn, fout);
  };

  run_layer(x, 3, W1, b1, g1, be1, 1, f1);
  run_layer(f1, 64, W2, b2, nullptr, nullptr, 0, f2);
  run_layer(f2, 64, W3, b3, g3, be3, 1, f3);
  run_layer(f3, 64, W4, b4, nullptr, nullptr, 0, f4);
  pool1_kernel<<<256, 256, 0, stream>>>(f1, f2, f3, f4, n_pts, Ppart);
  pool2_kernel<<<64, 256, 0, stream>>>(Ppart, Pb);
  head_kernel<<<64, 128, 0, stream>>>(Pb, Wp, bp, out);
}

// Round 6
// 1470.173 us; speedup vs baseline: 1.0520x; 1.0520x over previous
//
#include <hip/hip_runtime.h>
#include <hip/hip_bf16.h>

constexpr int N = 16384;   // points
constexpr int KNN = 10;
constexpr int CF = 64;     // feature channels per edgeconv
constexpr int NSPLIT = 6;  // col splits per row-group (grid = 128*6 = 768 = 3 blocks/CU)

#define FBIG 1e30f

typedef __attribute__((ext_vector_type(8))) __bf16 bfv8;
typedef __attribute__((ext_vector_type(4))) float f32x4;

// ---------- top-k insert (replace-max) ----------
#define TOPK_INSERT(dval, jval)                                            \
  if ((dval) < bmax) {                                                     \
    float mv = bd[0]; int slot = 0;                                        \
    _Pragma("unroll") for (int s_ = 1; s_ < 10; ++s_)                      \
      if (bd[s_] > mv) { mv = bd[s_]; slot = s_; }                         \
    _Pragma("unroll") for (int s_ = 0; s_ < 10; ++s_)                      \
      if (slot == s_) { bd[s_] = (dval); bi[s_] = (jval); }                \
    bmax = bd[0];                                                          \
    _Pragma("unroll") for (int s_ = 1; s_ < 10; ++s_)                      \
      bmax = fmaxf(bmax, bd[s_]);                                          \
  }

__device__ inline ushort bf16_rne(float x) {
  unsigned u = __float_as_uint(x);
  return (ushort)((u + 0x7FFFu + ((u >> 16) & 1u)) >> 16);
}
__device__ inline float bf16_to_f(ushort h) { return __uint_as_float(((unsigned)h) << 16); }

// ---------- pack x (3ch) into float4 with sq norm ----------
__global__ __launch_bounds__(256) void pack3_kernel(const float* __restrict__ X,
                                                    float4* __restrict__ xp) {
  int i = blockIdx.x * 256 + threadIdx.x;
  float x0 = X[3 * i], x1 = X[3 * i + 1], x2 = X[3 * i + 2];
  float s = fmaf(x0, x0, fmaf(x1, x1, x2 * x2));
  xp[i] = make_float4(x0, x1, x2, s);
}

// ---------- fused 64-ch prep: bf16 hi/lo split + sq norm (one pass over X) ----------
__global__ __launch_bounds__(256) void prep128s_kernel(const float* __restrict__ X,
                                                       ushort* __restrict__ Xp,
                                                       float* __restrict__ sq) {
  int i = blockIdx.x * 256 + threadIdx.x;  // one float4 per thread; 16 threads per row
  int n = i >> 4, k4 = (i & 15) << 2;
  float4 v = ((const float4*)X)[i];
  float vv[4] = {v.x, v.y, v.z, v.w};
  ushort h[4], lo[4];
#pragma unroll
  for (int k = 0; k < 4; ++k) {
    h[k] = bf16_rne(vv[k]);
    lo[k] = bf16_rne(vv[k] - bf16_to_f(h[k]));
  }
  ushort* row = Xp + (size_t)n * 128;
  *(ushort4*)(row + k4) = make_ushort4(h[0], h[1], h[2], h[3]);
  *(ushort4*)(row + 64 + k4) = make_ushort4(lo[0], lo[1], lo[2], lo[3]);
  float ps = fmaf(vv[0], vv[0], fmaf(vv[1], vv[1], fmaf(vv[2], vv[2], vv[3] * vv[3])));
#pragma unroll
  for (int m = 1; m < 16; m <<= 1) ps += __shfl_xor(ps, m, 16);
  if ((threadIdx.x & 15) == 0) sq[n] = ps;
}

// ============== wave-independent kNN ==============
// Each wave privately owns 32 rows (2 MFMA row-tiles) and scans chunks of 16 cols.
// NO __syncthreads anywhere: filter/append/drain use a per-wave LDS slice; DS ops
// from one wave are pipeline-ordered, wave_barrier() pins compiler ordering.
// Per chunk: <=16 appends/row (16 cols) -> buf stride 17 never overflows.
// Drain EVERY chunk (tau always fresh). Owner lane l (<32) keeps row l's top-10 in regs.
// grid = 128 rowgroups (128 rows: 4 waves x 32) x NSPLIT chunk-ranges.

#define KNN_WAVE_SHARED                                                    \
  __shared__ float bufD[4][32 * 17];                                       \
  __shared__ ushort bufI[4][32 * 18];                                      \
  __shared__ __align__(16) float tauS[4][32];                              \
  __shared__ int cntS[4][32];

#define KNN_WAVE_INIT                                                      \
  if (l < 32) { tauS[w][l] = FBIG; cntS[w][l] = 0; }                       \
  __builtin_amdgcn_wave_barrier();

#define KNN_WAVE_DRAIN                                                     \
  __builtin_amdgcn_wave_barrier();                                         \
  if (l < 32) {                                                            \
    const int c = cntS[w][l];                                              \
    if (c) {                                                               \
      const float* bD = &bufD[w][l * 17];                                  \
      const ushort* bI = &bufI[w][l * 18];                                 \
      _Pragma("unroll 1") for (int j = 0; j < c; ++j) {                    \
        float d = bD[j];                                                   \
        int ii = (int)bI[j];                                               \
        TOPK_INSERT(d, ii);                                                \
      }                                                                    \
      cntS[w][l] = 0;                                                      \
      tauS[w][l] = bmax;                                                   \
    }                                                                      \
  }                                                                        \
  __builtin_amdgcn_wave_barrier();

#define KNN_WAVE_OUT                                                       \
  if (l < 32) {                                                            \
    const int row = wbase + l;                                             \
    float* dp = dpart + ((size_t)cs * N + row) * 10;                       \
    int* ip = ipart + ((size_t)cs * N + row) * 10;                         \
    _Pragma("unroll") for (int s = 0; s < 10; ++s) {                       \
      dp[s] = bd[s];                                                       \
      ip[s] = bi[s];                                                       \
    }                                                                      \
  }

// ---------- kNN for C=3, exact fp32 distances (cancellation-sensitive: keep fp32!) ----------
__global__ __launch_bounds__(256, 3) void knn3w_kernel(const float4* __restrict__ xp,
                                                       float* __restrict__ dpart,
                                                       int* __restrict__ ipart) {
  KNN_WAVE_SHARED
  const int tid = threadIdx.x;
  const int w = tid >> 6;
  const int l = tid & 63;
  const int lp = l & 15;
  const int g = l >> 4;
  const int rg = blockIdx.x / NSPLIT;
  const int cs = blockIdx.x % NSPLIT;
  const int wbase = rg * 128 + w * 32;
  const int c0 = (1024 * cs) / NSPLIT, c1 = (1024 * (cs + 1)) / NSPLIT;

  KNN_WAVE_INIT

  // 8 pinned row float4s: rows wbase + rt*16 + g*4 + r
  float4 rw[8];
#pragma unroll
  for (int rt = 0; rt < 2; ++rt)
#pragma unroll
    for (int r = 0; r < 4; ++r) rw[rt * 4 + r] = xp[wbase + rt * 16 + g * 4 + r];

  float bd[10]; int bi[10]; float bmax = FBIG;
#pragma unroll
  for (int s = 0; s < 10; ++s) { bd[s] = FBIG; bi[s] = 0x7ffffff; }

  float4 oc = xp[c0 * 16 + lp];
  for (int t = c0; t < c1; ++t) {
    float4 on;
    if (t + 1 < c1) on = xp[(t + 1) * 16 + lp];  // prefetch
    const int lcol = t * 16 + lp;
#pragma unroll
    for (int rt = 0; rt < 2; ++rt) {
      f32x4 taur = *(const f32x4*)&tauS[w][rt * 16 + g * 4];
#pragma unroll
      for (int r = 0; r < 4; ++r) {
        const float4 m = rw[rt * 4 + r];
        float dot = fmaf(m.x, oc.x, fmaf(m.y, oc.y, m.z * oc.z));
        float d = fmaf(-2.f, dot, m.w + oc.w);  // same chain as validated knn3
        if (d < taur[r]) {
          int rloc = rt * 16 + g * 4 + r;
          int pos = atomicAdd(&cntS[w][rloc], 1);
          bufD[w][rloc * 17 + pos] = d;
          bufI[w][rloc * 18 + pos] = (ushort)lcol;
        }
      }
    }
    KNN_WAVE_DRAIN
    oc = on;
  }
  KNN_WAVE_OUT
}

// ---------- kNN for C=64 via bf16-split MFMA (hi.hi + hi.lo + lo.hi) ----------
__global__ __launch_bounds__(256, 3) void knn64w_kernel(const ushort* __restrict__ Xp,
                                                        const float* __restrict__ sq,
                                                        float* __restrict__ dpart,
                                                        int* __restrict__ ipart) {
  KNN_WAVE_SHARED
  const int tid = threadIdx.x;
  const int w = tid >> 6;
  const int l = tid & 63;
  const int lp = l & 15;
  const int g = l >> 4;
  const int lk = g * 8;
  const int rg = blockIdx.x / NSPLIT;
  const int cs = blockIdx.x % NSPLIT;
  const int wbase = rg * 128 + w * 32;
  const int c0 = (1024 * cs) / NSPLIT, c1 = (1024 * (cs + 1)) / NSPLIT;

  KNN_WAVE_INIT

  // A fragments for 2 row-tiles: 8 bfv8 = 32 VGPRs (small enough to stay pinned)
  bfv8 aH1[2], aH2[2], aL1[2], aL2[2];
#pragma unroll
  for (int rt = 0; rt < 2; ++rt) {
    const size_t ao = (size_t)(wbase + rt * 16 + lp) * 128 + lk;
    aH1[rt] = *(const bfv8*)&Xp[ao];
    aH2[rt] = *(const bfv8*)&Xp[ao + 32];
    aL1[rt] = *(const bfv8*)&Xp[ao + 64];
    aL2[rt] = *(const bfv8*)&Xp[ao + 96];
  }
  float sqi[8];
#pragma unroll
  for (int rt = 0; rt < 2; ++rt)
#pragma unroll
    for (int r = 0; r < 4; ++r) sqi[rt * 4 + r] = sq[wbase + rt * 16 + g * 4 + r];

  float bd[10]; int bi[10]; float bmax = FBIG;
#pragma unroll
  for (int s = 0; s < 10; ++s) { bd[s] = FBIG; bi[s] = 0x7ffffff; }

  bfv8 bc[4]; float sjc;
  {
    const int bcol = c0 * 16 + lp;
    const size_t bo = (size_t)bcol * 128 + lk;
    bc[0] = *(const bfv8*)&Xp[bo];
    bc[1] = *(const bfv8*)&Xp[bo + 32];
    bc[2] = *(const bfv8*)&Xp[bo + 64];
    bc[3] = *(const bfv8*)&Xp[bo + 96];
    sjc = sq[bcol];
  }

  for (int t = c0; t < c1; ++t) {
    bfv8 bn[4]; float sjn;
    if (t + 1 < c1) {  // prefetch next 16-col chunk
      const int bcol = (t + 1) * 16 + lp;
      const size_t bo = (size_t)bcol * 128 + lk;
      bn[0] = *(const bfv8*)&Xp[bo];
      bn[1] = *(const bfv8*)&Xp[bo + 32];
      bn[2] = *(const bfv8*)&Xp[bo + 64];
      bn[3] = *(const bfv8*)&Xp[bo + 96];
      sjn = sq[bcol];
    }
    const int lcol = t * 16 + lp;
#pragma unroll
    for (int rt = 0; rt < 2; ++rt) {
      f32x4 acc = {0.f, 0.f, 0.f, 0.f};
      acc = __builtin_amdgcn_mfma_f32_16x16x32_bf16(aH1[rt], bc[0], acc, 0, 0, 0);
      acc = __builtin_amdgcn_mfma_f32_16x16x32_bf16(aH2[rt], bc[1], acc, 0, 0, 0);
      acc = __builtin_amdgcn_mfma_f32_16x16x32_bf16(aH1[rt], bc[2], acc, 0, 0, 0);
      acc = __builtin_amdgcn_mfma_f32_16x16x32_bf16(aH2[rt], bc[3], acc, 0, 0, 0);
      acc = __builtin_amdgcn_mfma_f32_16x16x32_bf16(aL1[rt], bc[0], acc, 0, 0, 0);
      acc = __builtin_amdgcn_mfma_f32_16x16x32_bf16(aL2[rt], bc[1], acc, 0, 0, 0);
      f32x4 taur = *(const f32x4*)&tauS[w][rt * 16 + g * 4];
#pragma unroll
      for (int r = 0; r < 4; ++r) {
        float d = fmaf(-2.f, acc[r], sqi[rt * 4 + r] + sjc);
        if (d < taur[r]) {
          int rloc = rt * 16 + g * 4 + r;
          int pos = atomicAdd(&cntS[w][rloc], 1);
          bufD[w][rloc * 17 + pos] = d;
          bufI[w][rloc * 18 + pos] = (ushort)lcol;
        }
      }
    }
    KNN_WAVE_DRAIN
    bc[0] = bn[0]; bc[1] = bn[1]; bc[2] = bn[2]; bc[3] = bn[3]; sjc = sjn;
  }
  KNN_WAVE_OUT
}

// ---------- merge S partial top-10 lists per row ----------
template <int S>
__global__ __launch_bounds__(256) void merge_kernel(const float* __restrict__ dpart,
                                                    const int* __restrict__ ipart,
                                                    int* __restrict__ idx_out) {
  const int row = blockIdx.x * 256 + threadIdx.x;
  float d[S * 10]; int id_[S * 10];
#pragma unroll
  for (int p = 0; p < S; ++p)
#pragma unroll
    for (int s = 0; s < 10; ++s) {
      d[p * 10 + s] = dpart[((size_t)p * N + row) * 10 + s];
      id_[p * 10 + s] = ipart[((size_t)p * N + row) * 10 + s];
    }
#pragma unroll
  for (int t = 0; t < 10; ++t) {
    float dm = d[0]; int im = id_[0]; int slot = 0;
#pragma unroll
    for (int e = 1; e < S * 10; ++e) {
      bool better = (d[e] < dm) || (d[e] == dm && id_[e] < im);
      if (better) { dm = d[e]; im = id_[e]; slot = e; }
    }
    idx_out[(size_t)row * 10 + t] = im;
#pragma unroll
    for (int e = 0; e < S * 10; ++e)
      if (e == slot) d[e] = FBIG;
  }
}

// ---------- u = x*W_bot ; v = x*(W_top - W_bot) + b ----------
__global__ __launch_bounds__(256) void uv_kernel(const float* __restrict__ Xf, int CIN,
                                                 const float* __restrict__ W,
                                                 const float* __restrict__ bias,
                                                 float* __restrict__ U, float* __restrict__ V) {
  int tid = threadIdx.x;
  int c = tid & 63, p = tid >> 6;
  int n = blockIdx.x * 4 + p;
  const float* xr = Xf + (size_t)n * CIN;
  float vt = 0.f, vb = 0.f;
  for (int m = 0; m < CIN; ++m) {
    float xm = xr[m];
    vt = fmaf(xm, W[m * 64 + c], vt);
    vb = fmaf(xm, W[(CIN + m) * 64 + c], vb);
  }
  U[(size_t)n * 64 + c] = vb;
  V[(size_t)n * 64 + c] = vt - vb + bias[c];
}

// ---------- BN batch stats ----------
__global__ __launch_bounds__(256) void stats_kernel(const float* __restrict__ U,
                                                    const float* __restrict__ V,
                                                    const int* __restrict__ idx,
                                                    float* __restrict__ accum) {
  int tid = threadIdx.x;
  int c = tid & 63, p = tid >> 6;
  int base = blockIdx.x * 64;  // 256 blocks x 64 points
  float s = 0.f, s2 = 0.f;
  for (int ch = 0; ch < 16; ++ch) {
    int n = base + ch * 4 + p;
    float vn = V[(size_t)n * 64 + c];
    const int* in_ = idx + (size_t)n * 10;
#pragma unroll
    for (int k = 0; k < 10; ++k) {
      float h = vn + U[(size_t)in_[k] * 64 + c];
      s += h;
      s2 = fmaf(h, h, s2);
    }
  }
  __shared__ float red[256], red2[256];
  red[tid] = s; red2[tid] = s2;
  __syncthreads();
  if (tid < 64) {
    float ts = red[tid] + red[64 + tid] + red[128 + tid] + red[192 + tid];
    float t2 = red2[tid] + red2[64 + tid] + red2[128 + tid] + red2[192 + tid];
    atomicAdd(&accum[tid], ts);
    atomicAdd(&accum[64 + tid], t2);
  }
}

__global__ void bnfin_kernel(const float* __restrict__ accum,
                             const float* __restrict__ gamma,
                             const float* __restrict__ beta,
                             float* __restrict__ scale, float* __restrict__ shift) {
  int c = threadIdx.x;  // 64
  float inv = 1.f / (float)(N * KNN);
  float mu = accum[c] * inv;
  float var = accum[64 + c] * inv - mu * mu;
  float sc = gamma[c] * rsqrtf(var + 1e-5f);
  scale[c] = sc;
  shift[c] = fmaf(-mu, sc, beta[c]);
}

// ---------- apply (BN) + ReLU + max over k ----------
__global__ __launch_bounds__(256) void apply_kernel(const float* __restrict__ U,
                                                    const float* __restrict__ V,
                                                    const int* __restrict__ idx,
                                                    const float* __restrict__ scale,
                                                    const float* __restrict__ shift,
                                                    int use_bn, float* __restrict__ Fout) {
  int tid = threadIdx.x;
  int c = tid & 63, p = tid >> 6;
  int n = blockIdx.x * 4 + p;
  float sc = use_bn ? scale[c] : 1.f;
  float sh = use_bn ? shift[c] : 0.f;
  float vn = V[(size_t)n * 64 + c];
  const int* in_ = idx + (size_t)n * 10;
  float m = 0.f;
#pragma unroll
  for (int k = 0; k < 10; ++k) {
    float h = vn + U[(size_t)in_[k] * 64 + c];
    m = fmaxf(m, fmaf(h, sc, sh));
  }
  Fout[(size_t)n * 64 + c] = m;
}

// ---------- segment max pooling, 2-stage ----------
__global__ __launch_bounds__(256) void pool1_kernel(const float* __restrict__ f1,
                                                    const float* __restrict__ f2,
                                                    const float* __restrict__ f3,
                                                    const float* __restrict__ f4,
                                                    const int* __restrict__ n_pts,
                                                    float* __restrict__ Pp) {
  int b = blockIdx.x >> 2;
  int q = blockIdx.x & 3;
  int c = threadIdx.x;
  int off = 0;
  for (int i = 0; i < b; ++i) off += n_pts[i];
  int cnt_ = n_pts[b];
  int s0 = off + (cnt_ * q) / 4;
  int s1 = off + (cnt_ * (q + 1)) / 4;
  const float* f = (c < 64) ? f1 : (c < 128) ? f2 : (c < 192) ? f3 : f4;
  int ch = c & 63;
  float m = -3.4e38f;
  for (int t = s0; t < s1; ++t) m = fmaxf(m, f[(size_t)t * 64 + ch]);
  Pp[((size_t)q * 64 + b) * 256 + c] = m;
}

__global__ __launch_bounds__(256) void pool2_kernel(const float* __restrict__ Pp,
                                                    float* __restrict__ P) {
  int b = blockIdx.x;
  int c = threadIdx.x;
  float m = Pp[(size_t)b * 256 + c];
#pragma unroll
  for (int q = 1; q < 4; ++q) m = fmaxf(m, Pp[((size_t)q * 64 + b) * 256 + c]);
  P[b * 256 + c] = m;
}

// ---------- head: tanh(P@Wp + bp), L2 normalize rows ----------
__global__ __launch_bounds__(128) void head_kernel(const float* __restrict__ P,
                                                   const float* __restrict__ Wp,
                                                   const float* __restrict__ bp,
                                                   float* __restrict__ out) {
  int b = blockIdx.x;
  int c = threadIdx.x;
  __shared__ float ps[256];
  ps[c] = P[b * 256 + c];
  ps[128 + c] = P[b * 256 + 128 + c];
  __syncthreads();
  float acc = bp[c];
  for (int m = 0; m < 256; ++m) acc = fmaf(ps[m], Wp[m * 128 + c], acc);
  float t = tanhf(acc);
  __shared__ float red[128];
  red[c] = t * t;
  __syncthreads();
  for (int s = 64; s > 0; s >>= 1) {
    if (c < s) red[c] += red[c + s];
    __syncthreads();
  }
  float nrm = sqrtf(red[0]);
  out[b * 128 + c] = t / (nrm + 1e-9f);
}

extern "C" void kernel_launch(void* const* d_in, const int* in_sizes, int n_in,
                              void* d_out, int out_size, void* d_ws, size_t ws_size,
                              hipStream_t stream) {
  const float* x = (const float*)d_in[0];
  const int* n_pts = (const int*)d_in[1];
  const float* W1 = (const float*)d_in[2];
  const float* b1 = (const float*)d_in[3];
  const float* g1 = (const float*)d_in[4];
  const float* be1 = (const float*)d_in[5];
  const float* W2 = (const float*)d_in[6];
  const float* b2 = (const float*)d_in[7];
  const float* W3 = (const float*)d_in[8];
  const float* b3 = (const float*)d_in[9];
  const float* g3 = (const float*)d_in[10];
  const float* be3 = (const float*)d_in[11];
  const float* W4 = (const float*)d_in[12];
  const float* b4 = (const float*)d_in[13];
  const float* Wp = (const float*)d_in[14];
  const float* bp = (const float*)d_in[15];
  float* out = (float*)d_out;

  char* w = (char*)d_ws;
  auto alloc = [&](size_t bytes) {
    char* p = w;
    w += (bytes + 255) & ~(size_t)255;
    return p;
  };
  const size_t FS = (size_t)N * 64 * 4;
  float* f1 = (float*)alloc(FS);
  float* f2 = (float*)alloc(FS);
  float* f3 = (float*)alloc(FS);
  float* f4 = (float*)alloc(FS);
  float* Ub = (float*)alloc(FS);   // overlaid: Xp128 (N*128 ushorts = FS bytes)
  float* Vb = (float*)alloc(FS);   // overlaid: xp (N float4 = FS/4)
  float* sqb = (float*)alloc((size_t)N * 4);
  float* dpartf = (float*)alloc((size_t)NSPLIT * N * 10 * 4);
  int* iparti = (int*)alloc((size_t)NSPLIT * N * 10 * 4);
  int* idxb = (int*)alloc((size_t)N * 10 * 4);
  float* accum = (float*)alloc(512);
  float* scaleb = (float*)alloc(256);
  float* shiftb = (float*)alloc(256);
  float* Pb = (float*)alloc((size_t)64 * 256 * 4);
  float* Ppart = (float*)alloc((size_t)4 * 64 * 256 * 4);
  ushort* Xp128 = (ushort*)Ub;
  float4* xp = (float4*)Vb;
  (void)ws_size; (void)n_in; (void)in_sizes; (void)out_size;

  auto run_layer = [&](const float* fin, int cin, const float* W, const float* b,
                       const float* g, const float* be, int use_bn, float* fout) {
    if (cin == 3) {
      pack3_kernel<<<N / 256, 256, 0, stream>>>(fin, xp);
      knn3w_kernel<<<128 * NSPLIT, 256, 0, stream>>>(xp, dpartf, iparti);
    } else {
      prep128s_kernel<<<N * 64 / 4 / 256, 256, 0, stream>>>(fin, Xp128, sqb);
      knn64w_kernel<<<128 * NSPLIT, 256, 0, stream>>>(Xp128, sqb, dpartf, iparti);
    }
    merge_kernel<NSPLIT><<<N / 256, 256, 0, stream>>>(dpartf, iparti, idxb);
    uv_kernel<<<N / 4, 256, 0, stream>>>(fin, cin, W, b, Ub, Vb);
    if (use_bn) {
      hipMemsetAsync(accum, 0, 512, stream);
      stats_kernel<<<256, 256, 0, stream>>>(Ub, Vb, idxb, accum);
      bnfin_kernel<<<1, 64, 0, stream>>>(accum, g, be, scaleb, shiftb);
    }
    apply_kernel<<<N / 4, 256, 0, stream>>>(Ub, Vb, idxb, scaleb, shiftb, use_bn, fout);
  };

  run_layer(x, 3, W1, b1, g1, be1, 1, f1);
  run_layer(f1, 64, W2, b2, nullptr, nullptr, 0, f2);
  run_layer(f2, 64, W3, b3, g3, be3, 1, f3);
  run_layer(f3, 64, W4, b4, nullptr, nullptr, 0, f4);
  pool1_kernel<<<256, 256, 0, stream>>>(f1, f2, f3, f4, n_pts, Ppart);
  pool2_kernel<<<64, 256, 0, stream>>>(Ppart, Pb);
  head_kernel<<<64, 128, 0, stream>>>(Pb, Wp, bp, out);
}